// Round 15
// baseline (152.830 us; speedup 1.0000x reference)
//
#include <hip/hip_runtime.h>

#define IN_DIM 128
#define HID 64
#define STAGE_CAP 12288

// ---------------- bucket histogram: per-block partials (no global atomics/memset) ----------------
__global__ __launch_bounds__(256) void k_bin_count(const int* __restrict__ dst, int E,
                                                   int* __restrict__ hist2d) {
    __shared__ int h[256];
    int tid = threadIdx.x;
    h[tid] = 0;
    __syncthreads();
    int base = blockIdx.x * 4096;
    int end = min(base + 4096, E);
    for (int i = base + tid; i < end; i += 256) atomicAdd(&h[dst[i] >> 8], 1);
    __syncthreads();
    hist2d[blockIdx.x * 256 + tid] = h[tid];
}

// ---------------- bucket exclusive scan (sums 2D partials) + gcur=0 + sentinels ----------------
__global__ __launch_bounds__(256) void k_bucket_scan(const int* __restrict__ hist2d, int eblk,
                                                     int* __restrict__ bbase,
                                                     int* __restrict__ gcur,
                                                     int* __restrict__ row_start, int N, int E) {
    int tid = threadIdx.x, lane = tid & 63, wid = tid >> 6;
    int v = 0;
    for (int k = 0; k < eblk; ++k) v += hist2d[k * 256 + tid];
    int orig = v;
    for (int off = 1; off < 64; off <<= 1) {
        int t = __shfl_up(v, off);
        if (lane >= off) v += t;
    }
    __shared__ int ws[4];
    if (lane == 63) ws[wid] = v;
    __syncthreads();
    int woff = 0;
    for (int w = 0; w < wid; ++w) woff += ws[w];
    bbase[tid] = woff + v - orig;
    gcur[tid] = 0;
    if (tid == 0) {
        bbase[256] = E;
        row_start[N] = E;
    }
}

// ---------------- CSR build, phase A: bucket-chunked scatter (N < 65536) ----------------
__global__ __launch_bounds__(512) void k_bin_scatter(const int* __restrict__ src,
                                                     const int* __restrict__ dst, int E,
                                                     const int* __restrict__ bbase,
                                                     int* __restrict__ gcur,
                                                     unsigned* __restrict__ ebuf) {
    __shared__ int hist[256];
    __shared__ int gbase[256];
    int tid = threadIdx.x;
    for (int i = tid; i < 256; i += 512) hist[i] = 0;
    __syncthreads();
    int base = blockIdx.x * 4096;
    int pk[8], bkt[8], rnk[8];
#pragma unroll
    for (int i = 0; i < 8; ++i) {
        int e = base + tid + i * 512;
        if (e < E) {
            int s = src[e];
            int d = dst[e];
            bkt[i] = d >> 8;
            pk[i] = ((d & 255) << 16) | s;
            rnk[i] = atomicAdd(&hist[bkt[i]], 1);
        } else {
            bkt[i] = -1;
        }
    }
    __syncthreads();
    for (int b = tid; b < 256; b += 512) {
        int c = hist[b];
        if (c > 0) gbase[b] = bbase[b] + atomicAdd(&gcur[b], c);
    }
    __syncthreads();
#pragma unroll
    for (int i = 0; i < 8; ++i) {
        if (bkt[i] >= 0) ebuf[gbase[bkt[i]] + rnk[i]] = (unsigned)pk[i];
    }
}

// ---------------- CSR build, phase B (fused): degree+scan -> row_start, dis ; LDS sort ----------------
__global__ __launch_bounds__(512) void k_bin_sort(const unsigned* __restrict__ ebuf,
                                                  const int* __restrict__ bbase, int N, int E,
                                                  int* __restrict__ row_start,
                                                  float* __restrict__ dis,
                                                  int* __restrict__ csr_src) {
    __shared__ int ldeg[256];
    __shared__ int loff[256];
    __shared__ int lcur[256];
    __shared__ int wsum[8];
    __shared__ unsigned short stage[STAGE_CAP];
    int tid = threadIdx.x;
    int node0 = blockIdx.x << 8;
    int nnode = min(256, N - node0);
    for (int i = tid; i < 256; i += 512) {
        ldeg[i] = 0;
        lcur[i] = 0;
    }
    __syncthreads();
    int bstart = bbase[blockIdx.x];
    int bend = bbase[blockIdx.x + 1];
    int cnt = bend - bstart;
    for (int i = tid; i < cnt; i += 512) {
        unsigned u = ebuf[bstart + i];
        atomicAdd(&ldeg[(u >> 16) & 255], 1);
    }
    __syncthreads();
    int lane = tid & 63, wid = tid >> 6;
    int v = 0, orig = 0;
    if (tid < 256) {
        orig = ldeg[tid];
        v = orig;
    }
    for (int off = 1; off < 64; off <<= 1) {
        int t = __shfl_up(v, off);
        if (lane >= off) v += t;
    }
    if (lane == 63) wsum[wid] = v;
    __syncthreads();
    if (tid < 256) {
        int woff = 0;
        for (int w = 0; w < wid && w < 4; ++w) woff += wsum[w];
        int excl = woff + v - orig;
        loff[tid] = excl;
        if (tid < nnode) {
            row_start[node0 + tid] = bstart + excl;
            dis[node0 + tid] = rsqrtf((float)(orig + 1));
        }
    }
    __syncthreads();
    if (cnt <= STAGE_CAP) {
        for (int i = tid; i < cnt; i += 512) {
            unsigned u = ebuf[bstart + i];
            int dlo = (u >> 16) & 255;
            int pos = loff[dlo] + atomicAdd(&lcur[dlo], 1);
            stage[pos] = (unsigned short)(u & 0xFFFF);
        }
        __syncthreads();
        for (int i = tid; i < cnt; i += 512) csr_src[bstart + i] = (int)stage[i];
    } else {
        for (int i = tid; i < cnt; i += 512) {
            unsigned u = ebuf[bstart + i];
            int dlo = (u >> 16) & 255;
            int pos = bstart + loff[dlo] + atomicAdd(&lcur[dlo], 1);
            csr_src[pos] = (int)(u & 0xFFFF);
        }
    }
}

// ---------------- K-chunked tiled GEMM: out[r][c] = dis[r]*sum_k X[r][k]*W[k][c] ----------------
template <int K>
__global__ __launch_bounds__(256) void k_gemm_scale(const float* __restrict__ X,
                                                    const float* __restrict__ W,
                                                    const float* __restrict__ dis, int N,
                                                    float* __restrict__ out) {
    constexpr int CH = 64;
    constexpr int CHP = CH + 4;
    constexpr int KC = K / 4;
    __shared__ float Xs[64 * CHP];
    __shared__ float Ws[CH * 64];
    int tid = threadIdx.x;
    int row0 = blockIdx.x * 64;
    int cg = tid & 15;
    int rg = tid >> 4;
    float acc[4][4] = {};
    const float4* Wg = (const float4*)W;
    const float4* Xg = (const float4*)X;
    float4* Ws4 = (float4*)Ws;

#pragma unroll
    for (int k0 = 0; k0 < K; k0 += CH) {
        if (k0) __syncthreads();
        for (int i = tid; i < CH * 16; i += 256) Ws4[i] = Wg[k0 * 16 + i];
        for (int c = tid; c < 64 * 16; c += 256) {
            int r = c >> 4, k4 = c & 15;
            int row = row0 + r;
            float4 vv = make_float4(0.f, 0.f, 0.f, 0.f);
            if (row < N) vv = Xg[(size_t)row * KC + (k0 >> 2) + k4];
            *(float4*)&Xs[r * CHP + k4 * 4] = vv;
        }
        __syncthreads();
#pragma unroll 2
        for (int k = 0; k < CH; k += 4) {
            float4 w0 = *(float4*)&Ws[(k + 0) * 64 + cg * 4];
            float4 w1 = *(float4*)&Ws[(k + 1) * 64 + cg * 4];
            float4 w2 = *(float4*)&Ws[(k + 2) * 64 + cg * 4];
            float4 w3 = *(float4*)&Ws[(k + 3) * 64 + cg * 4];
#pragma unroll
            for (int i = 0; i < 4; ++i) {
                float4 xv = *(float4*)&Xs[(rg * 4 + i) * CHP + k];
                acc[i][0] += xv.x * w0.x + xv.y * w1.x + xv.z * w2.x + xv.w * w3.x;
                acc[i][1] += xv.x * w0.y + xv.y * w1.y + xv.z * w2.y + xv.w * w3.y;
                acc[i][2] += xv.x * w0.z + xv.y * w1.z + xv.z * w2.z + xv.w * w3.z;
                acc[i][3] += xv.x * w0.w + xv.y * w1.w + xv.z * w2.w + xv.w * w3.w;
            }
        }
    }
#pragma unroll
    for (int i = 0; i < 4; ++i) {
        int row = row0 + rg * 4 + i;
        if (row < N) {
            float s = dis[row];
            *(float4*)&out[(size_t)row * 64 + cg * 4] =
                make_float4(acc[i][0] * s, acc[i][1] * s, acc[i][2] * s, acc[i][3] * s);
        }
    }
}

// ---------------- gather-aggregate v7: 8 gathers in flight (scaled Hs, pure adds) ----------------
// lane = g*8 + t ; subgroup g handles edges jb+{0,8,16,24}+g; lane covers float4 t and t+8
__global__ __launch_bounds__(256) void k_aggregate(const float* __restrict__ Hs,
                                                   const int* __restrict__ row_start,
                                                   const int* __restrict__ csr_src,
                                                   const float* __restrict__ dis,
                                                   const float* __restrict__ bias, int N,
                                                   float* __restrict__ out) {
    const float4* Hs4 = (const float4*)Hs;
    int wave = threadIdx.x >> 6, lane = threadIdx.x & 63;
    int node = blockIdx.x * 4 + wave;
    if (node >= N) return;
    int t = lane & 7, g = lane >> 3;
    float4 a0 = make_float4(0.f, 0.f, 0.f, 0.f);
    float4 a1 = a0;
    if (g == 0) {
        a0 = Hs4[(size_t)node * 16 + t];
        a1 = Hs4[(size_t)node * 16 + t + 8];
    }
    int e0 = row_start[node], e1 = row_start[node + 1];
    for (int eb = e0; eb < e1; eb += 64) {
        int cnt = min(64, e1 - eb);
        int sv = (eb + lane < e1) ? csr_src[eb + lane] : 0;
        for (int jb = 0; jb < cnt; jb += 32) {
            int i0 = jb + g, i1 = jb + 8 + g, i2 = jb + 16 + g, i3 = jb + 24 + g;
            int s0 = __shfl(sv, i0 < cnt ? i0 : 0);
            int s1 = __shfl(sv, i1 < cnt ? i1 : 0);
            int s2 = __shfl(sv, i2 < cnt ? i2 : 0);
            int s3 = __shfl(sv, i3 < cnt ? i3 : 0);
            size_t b0 = (size_t)s0 * 16, b1 = (size_t)s1 * 16;
            size_t b2 = (size_t)s2 * 16, b3 = (size_t)s3 * 16;
            float4 z00 = Hs4[b0 + t], z01 = Hs4[b0 + t + 8];
            float4 z10 = Hs4[b1 + t], z11 = Hs4[b1 + t + 8];
            float4 z20 = Hs4[b2 + t], z21 = Hs4[b2 + t + 8];
            float4 z30 = Hs4[b3 + t], z31 = Hs4[b3 + t + 8];
            if (i0 < cnt) {
                a0.x += z00.x; a0.y += z00.y; a0.z += z00.z; a0.w += z00.w;
                a1.x += z01.x; a1.y += z01.y; a1.z += z01.z; a1.w += z01.w;
            }
            if (i1 < cnt) {
                a0.x += z10.x; a0.y += z10.y; a0.z += z10.z; a0.w += z10.w;
                a1.x += z11.x; a1.y += z11.y; a1.z += z11.z; a1.w += z11.w;
            }
            if (i2 < cnt) {
                a0.x += z20.x; a0.y += z20.y; a0.z += z20.z; a0.w += z20.w;
                a1.x += z21.x; a1.y += z21.y; a1.z += z21.z; a1.w += z21.w;
            }
            if (i3 < cnt) {
                a0.x += z30.x; a0.y += z30.y; a0.z += z30.z; a0.w += z30.w;
                a1.x += z31.x; a1.y += z31.y; a1.z += z31.z; a1.w += z31.w;
            }
        }
    }
#pragma unroll
    for (int off = 8; off < 64; off <<= 1) {
        a0.x += __shfl_xor(a0.x, off); a0.y += __shfl_xor(a0.y, off);
        a0.z += __shfl_xor(a0.z, off); a0.w += __shfl_xor(a0.w, off);
        a1.x += __shfl_xor(a1.x, off); a1.y += __shfl_xor(a1.y, off);
        a1.z += __shfl_xor(a1.z, off); a1.w += __shfl_xor(a1.w, off);
    }
    float sc = dis[node];
    const float4* b4 = (const float4*)bias;
    float4 b0 = b4[t], b1 = b4[t + 8];
    float4 v0, v1;
    v0.x = fmaxf(a0.x * sc + b0.x, 0.f); v0.y = fmaxf(a0.y * sc + b0.y, 0.f);
    v0.z = fmaxf(a0.z * sc + b0.z, 0.f); v0.w = fmaxf(a0.w * sc + b0.w, 0.f);
    v1.x = fmaxf(a1.x * sc + b1.x, 0.f); v1.y = fmaxf(a1.y * sc + b1.y, 0.f);
    v1.z = fmaxf(a1.z * sc + b1.z, 0.f); v1.w = fmaxf(a1.w * sc + b1.w, 0.f);
    if (g == 0) {
        float4* o4 = (float4*)out;
        o4[(size_t)node * 16 + t] = v0;
        o4[(size_t)node * 16 + t + 8] = v1;
    }
}

// ---------------- aggregate v7 + fused head ----------------
__global__ __launch_bounds__(256) void k_aggregate_head(const float* __restrict__ Hs,
                                                        const int* __restrict__ row_start,
                                                        const int* __restrict__ csr_src,
                                                        const float* __restrict__ dis,
                                                        const float* __restrict__ bias,
                                                        const float* __restrict__ Wl,
                                                        const float* __restrict__ bl, int N,
                                                        float* __restrict__ out) {
    const float4* Hs4 = (const float4*)Hs;
    int wave = threadIdx.x >> 6, lane = threadIdx.x & 63;
    int node = blockIdx.x * 4 + wave;
    if (node >= N) return;
    int t = lane & 7, g = lane >> 3;
    float4 a0 = make_float4(0.f, 0.f, 0.f, 0.f);
    float4 a1 = a0;
    if (g == 0) {
        a0 = Hs4[(size_t)node * 16 + t];
        a1 = Hs4[(size_t)node * 16 + t + 8];
    }
    int e0 = row_start[node], e1 = row_start[node + 1];
    for (int eb = e0; eb < e1; eb += 64) {
        int cnt = min(64, e1 - eb);
        int sv = (eb + lane < e1) ? csr_src[eb + lane] : 0;
        for (int jb = 0; jb < cnt; jb += 32) {
            int i0 = jb + g, i1 = jb + 8 + g, i2 = jb + 16 + g, i3 = jb + 24 + g;
            int s0 = __shfl(sv, i0 < cnt ? i0 : 0);
            int s1 = __shfl(sv, i1 < cnt ? i1 : 0);
            int s2 = __shfl(sv, i2 < cnt ? i2 : 0);
            int s3 = __shfl(sv, i3 < cnt ? i3 : 0);
            size_t b0 = (size_t)s0 * 16, b1 = (size_t)s1 * 16;
            size_t b2 = (size_t)s2 * 16, b3 = (size_t)s3 * 16;
            float4 z00 = Hs4[b0 + t], z01 = Hs4[b0 + t + 8];
            float4 z10 = Hs4[b1 + t], z11 = Hs4[b1 + t + 8];
            float4 z20 = Hs4[b2 + t], z21 = Hs4[b2 + t + 8];
            float4 z30 = Hs4[b3 + t], z31 = Hs4[b3 + t + 8];
            if (i0 < cnt) {
                a0.x += z00.x; a0.y += z00.y; a0.z += z00.z; a0.w += z00.w;
                a1.x += z01.x; a1.y += z01.y; a1.z += z01.z; a1.w += z01.w;
            }
            if (i1 < cnt) {
                a0.x += z10.x; a0.y += z10.y; a0.z += z10.z; a0.w += z10.w;
                a1.x += z11.x; a1.y += z11.y; a1.z += z11.z; a1.w += z11.w;
            }
            if (i2 < cnt) {
                a0.x += z20.x; a0.y += z20.y; a0.z += z20.z; a0.w += z20.w;
                a1.x += z21.x; a1.y += z21.y; a1.z += z21.z; a1.w += z21.w;
            }
            if (i3 < cnt) {
                a0.x += z30.x; a0.y += z30.y; a0.z += z30.z; a0.w += z30.w;
                a1.x += z31.x; a1.y += z31.y; a1.z += z31.z; a1.w += z31.w;
            }
        }
    }
#pragma unroll
    for (int off = 8; off < 64; off <<= 1) {
        a0.x += __shfl_xor(a0.x, off); a0.y += __shfl_xor(a0.y, off);
        a0.z += __shfl_xor(a0.z, off); a0.w += __shfl_xor(a0.w, off);
        a1.x += __shfl_xor(a1.x, off); a1.y += __shfl_xor(a1.y, off);
        a1.z += __shfl_xor(a1.z, off); a1.w += __shfl_xor(a1.w, off);
    }
    float sc = dis[node];
    const float4* b4 = (const float4*)bias;
    float4 b0 = b4[t], b1 = b4[t + 8];
    float4 v0, v1;
    v0.x = fmaxf(a0.x * sc + b0.x, 0.f); v0.y = fmaxf(a0.y * sc + b0.y, 0.f);
    v0.z = fmaxf(a0.z * sc + b0.z, 0.f); v0.w = fmaxf(a0.w * sc + b0.w, 0.f);
    v1.x = fmaxf(a1.x * sc + b1.x, 0.f); v1.y = fmaxf(a1.y * sc + b1.y, 0.f);
    v1.z = fmaxf(a1.z * sc + b1.z, 0.f); v1.w = fmaxf(a1.w * sc + b1.w, 0.f);
    int c0 = 4 * t, c1 = 32 + 4 * t;
    float p0 = v0.x * Wl[(c0 + 0) * 2] + v0.y * Wl[(c0 + 1) * 2] +
               v0.z * Wl[(c0 + 2) * 2] + v0.w * Wl[(c0 + 3) * 2] +
               v1.x * Wl[(c1 + 0) * 2] + v1.y * Wl[(c1 + 1) * 2] +
               v1.z * Wl[(c1 + 2) * 2] + v1.w * Wl[(c1 + 3) * 2];
    float p1 = v0.x * Wl[(c0 + 0) * 2 + 1] + v0.y * Wl[(c0 + 1) * 2 + 1] +
               v0.z * Wl[(c0 + 2) * 2 + 1] + v0.w * Wl[(c0 + 3) * 2 + 1] +
               v1.x * Wl[(c1 + 0) * 2 + 1] + v1.y * Wl[(c1 + 1) * 2 + 1] +
               v1.z * Wl[(c1 + 2) * 2 + 1] + v1.w * Wl[(c1 + 3) * 2 + 1];
    p0 += __shfl_xor(p0, 1); p1 += __shfl_xor(p1, 1);
    p0 += __shfl_xor(p0, 2); p1 += __shfl_xor(p1, 2);
    p0 += __shfl_xor(p0, 4); p1 += __shfl_xor(p1, 4);
    if (lane == 0) {
        out[node * 2 + 0] = p0 + bl[0];
        out[node * 2 + 1] = p1 + bl[1];
    }
}

extern "C" void kernel_launch(void* const* d_in, const int* in_sizes, int n_in,
                              void* d_out, int out_size, void* d_ws, size_t ws_size,
                              hipStream_t stream) {
    const float* x  = (const float*)d_in[0];
    const int*   ei = (const int*)d_in[1];
    const float* W1 = (const float*)d_in[2];
    const float* b1 = (const float*)d_in[3];
    const float* W2 = (const float*)d_in[4];
    const float* b2 = (const float*)d_in[5];
    const float* Wl = (const float*)d_in[6];
    const float* bl = (const float*)d_in[7];

    const int N = in_sizes[0] / IN_DIM;   // 50000 (< 65536 required by packing)
    const int E = in_sizes[1] / 2;        // 800000
    const int* src = ei;
    const int* dst = ei + E;

    char* ws = (char*)d_ws;
    size_t off = 0;
    auto alloc = [&](size_t bytes) -> void* {
        void* p = ws + off;
        off = (off + bytes + 255) & ~(size_t)255;
        return p;
    };
    const int eblk = (E + 4095) / 4096;  // 196
    const int nb = (N + 255) / 256;      // 196
    int*   hist2d    = (int*)alloc((size_t)eblk * 256 * 4);
    int*   bbase     = (int*)alloc(257 * 4);
    int*   gcur      = (int*)alloc(256 * 4);
    int*   row_start = (int*)alloc(((size_t)N + 1) * 4);
    float* dis       = (float*)alloc((size_t)N * 4);
    int*   csr_src   = (int*)alloc((size_t)E * 4);
    float* bufA      = (float*)alloc((size_t)N * HID * 4);
    float* bufB      = (float*)alloc((size_t)N * HID * 4);
    unsigned* ebuf   = (unsigned*)bufA;  // alias: consumed by bin_sort before gemm1 writes bufA

    k_bin_count<<<eblk, 256, 0, stream>>>(dst, E, hist2d);
    k_bucket_scan<<<1, 256, 0, stream>>>(hist2d, eblk, bbase, gcur, row_start, N, E);
    k_bin_scatter<<<eblk, 512, 0, stream>>>(src, dst, E, bbase, gcur, ebuf);
    k_bin_sort<<<nb, 512, 0, stream>>>(ebuf, bbase, N, E, row_start, dis, csr_src);

    const int gblk = (N + 63) / 64;  // 782
    const int nblk = (N + 3) / 4;
    k_gemm_scale<IN_DIM><<<gblk, 256, 0, stream>>>(x, W1, dis, N, bufA);
    k_aggregate<<<nblk, 256, 0, stream>>>(bufA, row_start, csr_src, dis, b1, N, bufB);
    k_gemm_scale<HID><<<gblk, 256, 0, stream>>>(bufB, W2, dis, N, bufA);
    k_aggregate_head<<<nblk, 256, 0, stream>>>(bufA, row_start, csr_src, dis, b2, Wl, bl, N,
                                               (float*)d_out);
}

// Round 16
// 135.813 us; speedup vs baseline: 1.1253x; 1.1253x over previous
//
#include <hip/hip_runtime.h>

#define IN_DIM 128
#define HID 64
#define STAGE_CAP 12288

// ---------------- bucket histogram: bcnt[b] = #edges with dst>>8 == b ----------------
__global__ __launch_bounds__(256) void k_bin_count(const int* __restrict__ dst, int E,
                                                   int* __restrict__ bcnt) {
    __shared__ int h[256];
    int tid = threadIdx.x;
    h[tid] = 0;
    __syncthreads();
    int base = blockIdx.x * 4096;
    int end = min(base + 4096, E);
    for (int i = base + tid; i < end; i += 256) atomicAdd(&h[dst[i] >> 8], 1);
    __syncthreads();
    if (h[tid]) atomicAdd(&bcnt[tid], h[tid]);
}

// ---------------- bucket exclusive scan (256 entries) + gcur=0 + sentinels ----------------
__global__ __launch_bounds__(256) void k_bucket_scan(const int* __restrict__ bcnt,
                                                     int* __restrict__ bbase,
                                                     int* __restrict__ gcur,
                                                     int* __restrict__ row_start, int N, int E) {
    int tid = threadIdx.x, lane = tid & 63, wid = tid >> 6;
    int v = bcnt[tid], orig = v;
    for (int off = 1; off < 64; off <<= 1) {
        int t = __shfl_up(v, off);
        if (lane >= off) v += t;
    }
    __shared__ int ws[4];
    if (lane == 63) ws[wid] = v;
    __syncthreads();
    int woff = 0;
    for (int w = 0; w < wid; ++w) woff += ws[w];
    bbase[tid] = woff + v - orig;
    gcur[tid] = 0;
    if (tid == 0) {
        bbase[256] = E;
        row_start[N] = E;
    }
}

// ---------------- CSR build, phase A: bucket-chunked scatter (N < 65536) ----------------
__global__ __launch_bounds__(512) void k_bin_scatter(const int* __restrict__ src,
                                                     const int* __restrict__ dst, int E,
                                                     const int* __restrict__ bbase,
                                                     int* __restrict__ gcur,
                                                     unsigned* __restrict__ ebuf) {
    __shared__ int hist[256];
    __shared__ int gbase[256];
    int tid = threadIdx.x;
    for (int i = tid; i < 256; i += 512) hist[i] = 0;
    __syncthreads();
    int base = blockIdx.x * 4096;
    int pk[8], bkt[8], rnk[8];
#pragma unroll
    for (int i = 0; i < 8; ++i) {
        int e = base + tid + i * 512;
        if (e < E) {
            int s = src[e];
            int d = dst[e];
            bkt[i] = d >> 8;
            pk[i] = ((d & 255) << 16) | s;
            rnk[i] = atomicAdd(&hist[bkt[i]], 1);
        } else {
            bkt[i] = -1;
        }
    }
    __syncthreads();
    for (int b = tid; b < 256; b += 512) {
        int c = hist[b];
        if (c > 0) gbase[b] = bbase[b] + atomicAdd(&gcur[b], c);
    }
    __syncthreads();
#pragma unroll
    for (int i = 0; i < 8; ++i) {
        if (bkt[i] >= 0) ebuf[gbase[bkt[i]] + rnk[i]] = (unsigned)pk[i];
    }
}

// ---------------- CSR build, phase B (fused): degree+scan -> row_start, dis ; LDS sort ----------------
__global__ __launch_bounds__(512) void k_bin_sort(const unsigned* __restrict__ ebuf,
                                                  const int* __restrict__ bbase, int N, int E,
                                                  int* __restrict__ row_start,
                                                  float* __restrict__ dis,
                                                  unsigned short* __restrict__ csr_src) {
    __shared__ int ldeg[256];
    __shared__ int loff[256];
    __shared__ int lcur[256];
    __shared__ int wsum[8];
    __shared__ unsigned short stage[STAGE_CAP];
    int tid = threadIdx.x;
    int node0 = blockIdx.x << 8;
    int nnode = min(256, N - node0);
    for (int i = tid; i < 256; i += 512) {
        ldeg[i] = 0;
        lcur[i] = 0;
    }
    __syncthreads();
    int bstart = bbase[blockIdx.x];
    int bend = bbase[blockIdx.x + 1];
    int cnt = bend - bstart;
    for (int i = tid; i < cnt; i += 512) {
        unsigned u = ebuf[bstart + i];
        atomicAdd(&ldeg[(u >> 16) & 255], 1);
    }
    __syncthreads();
    int lane = tid & 63, wid = tid >> 6;
    int v = 0, orig = 0;
    if (tid < 256) {
        orig = ldeg[tid];
        v = orig;
    }
    for (int off = 1; off < 64; off <<= 1) {
        int t = __shfl_up(v, off);
        if (lane >= off) v += t;
    }
    if (lane == 63) wsum[wid] = v;
    __syncthreads();
    if (tid < 256) {
        int woff = 0;
        for (int w = 0; w < wid && w < 4; ++w) woff += wsum[w];
        int excl = woff + v - orig;
        loff[tid] = excl;
        if (tid < nnode) {
            row_start[node0 + tid] = bstart + excl;
            dis[node0 + tid] = rsqrtf((float)(orig + 1));
        }
    }
    __syncthreads();
    if (cnt <= STAGE_CAP) {
        for (int i = tid; i < cnt; i += 512) {
            unsigned u = ebuf[bstart + i];
            int dlo = (u >> 16) & 255;
            int pos = loff[dlo] + atomicAdd(&lcur[dlo], 1);
            stage[pos] = (unsigned short)(u & 0xFFFF);
        }
        __syncthreads();
        for (int i = tid; i < cnt; i += 512) csr_src[bstart + i] = stage[i];
    } else {
        for (int i = tid; i < cnt; i += 512) {
            unsigned u = ebuf[bstart + i];
            int dlo = (u >> 16) & 255;
            int pos = bstart + loff[dlo] + atomicAdd(&lcur[dlo], 1);
            csr_src[pos] = (unsigned short)(u & 0xFFFF);
        }
    }
}

// ---------------- K-chunked tiled GEMM: out[r][c] = dis[r]*sum_k X[r][k]*W[k][c] ----------------
template <int K>
__global__ __launch_bounds__(256) void k_gemm_scale(const float* __restrict__ X,
                                                    const float* __restrict__ W,
                                                    const float* __restrict__ dis, int N,
                                                    float* __restrict__ out) {
    constexpr int CH = 64;
    constexpr int CHP = CH + 4;
    constexpr int KC = K / 4;
    __shared__ float Xs[64 * CHP];
    __shared__ float Ws[CH * 64];
    int tid = threadIdx.x;
    int row0 = blockIdx.x * 64;
    int cg = tid & 15;
    int rg = tid >> 4;
    float acc[4][4] = {};
    const float4* Wg = (const float4*)W;
    const float4* Xg = (const float4*)X;
    float4* Ws4 = (float4*)Ws;

#pragma unroll
    for (int k0 = 0; k0 < K; k0 += CH) {
        if (k0) __syncthreads();
        for (int i = tid; i < CH * 16; i += 256) Ws4[i] = Wg[k0 * 16 + i];
        for (int c = tid; c < 64 * 16; c += 256) {
            int r = c >> 4, k4 = c & 15;
            int row = row0 + r;
            float4 vv = make_float4(0.f, 0.f, 0.f, 0.f);
            if (row < N) vv = Xg[(size_t)row * KC + (k0 >> 2) + k4];
            *(float4*)&Xs[r * CHP + k4 * 4] = vv;
        }
        __syncthreads();
#pragma unroll 2
        for (int k = 0; k < CH; k += 4) {
            float4 w0 = *(float4*)&Ws[(k + 0) * 64 + cg * 4];
            float4 w1 = *(float4*)&Ws[(k + 1) * 64 + cg * 4];
            float4 w2 = *(float4*)&Ws[(k + 2) * 64 + cg * 4];
            float4 w3 = *(float4*)&Ws[(k + 3) * 64 + cg * 4];
#pragma unroll
            for (int i = 0; i < 4; ++i) {
                float4 xv = *(float4*)&Xs[(rg * 4 + i) * CHP + k];
                acc[i][0] += xv.x * w0.x + xv.y * w1.x + xv.z * w2.x + xv.w * w3.x;
                acc[i][1] += xv.x * w0.y + xv.y * w1.y + xv.z * w2.y + xv.w * w3.y;
                acc[i][2] += xv.x * w0.z + xv.y * w1.z + xv.z * w2.z + xv.w * w3.z;
                acc[i][3] += xv.x * w0.w + xv.y * w1.w + xv.z * w2.w + xv.w * w3.w;
            }
        }
    }
#pragma unroll
    for (int i = 0; i < 4; ++i) {
        int row = row0 + rg * 4 + i;
        if (row < N) {
            float s = dis[row];
            *(float4*)&out[(size_t)row * 64 + cg * 4] =
                make_float4(acc[i][0] * s, acc[i][1] * s, acc[i][2] * s, acc[i][3] * s);
        }
    }
}

// ---------------- gather-aggregate v7: 8 gathers in flight (scaled Hs, pure adds) ----------------
__global__ __launch_bounds__(256) void k_aggregate(const float* __restrict__ Hs,
                                                   const int* __restrict__ row_start,
                                                   const unsigned short* __restrict__ csr_src,
                                                   const float* __restrict__ dis,
                                                   const float* __restrict__ bias, int N,
                                                   float* __restrict__ out) {
    const float4* Hs4 = (const float4*)Hs;
    int wave = threadIdx.x >> 6, lane = threadIdx.x & 63;
    int node = blockIdx.x * 4 + wave;
    if (node >= N) return;
    int t = lane & 7, g = lane >> 3;
    float4 a0 = make_float4(0.f, 0.f, 0.f, 0.f);
    float4 a1 = a0;
    if (g == 0) {
        a0 = Hs4[(size_t)node * 16 + t];
        a1 = Hs4[(size_t)node * 16 + t + 8];
    }
    int e0 = row_start[node], e1 = row_start[node + 1];
    for (int eb = e0; eb < e1; eb += 64) {
        int cnt = min(64, e1 - eb);
        int sv = (eb + lane < e1) ? (int)csr_src[eb + lane] : 0;
        for (int jb = 0; jb < cnt; jb += 32) {
            int i0 = jb + g, i1 = jb + 8 + g, i2 = jb + 16 + g, i3 = jb + 24 + g;
            int s0 = __shfl(sv, i0 < cnt ? i0 : 0);
            int s1 = __shfl(sv, i1 < cnt ? i1 : 0);
            int s2 = __shfl(sv, i2 < cnt ? i2 : 0);
            int s3 = __shfl(sv, i3 < cnt ? i3 : 0);
            size_t b0 = (size_t)s0 * 16, b1 = (size_t)s1 * 16;
            size_t b2 = (size_t)s2 * 16, b3 = (size_t)s3 * 16;
            float4 z00 = Hs4[b0 + t], z01 = Hs4[b0 + t + 8];
            float4 z10 = Hs4[b1 + t], z11 = Hs4[b1 + t + 8];
            float4 z20 = Hs4[b2 + t], z21 = Hs4[b2 + t + 8];
            float4 z30 = Hs4[b3 + t], z31 = Hs4[b3 + t + 8];
            if (i0 < cnt) {
                a0.x += z00.x; a0.y += z00.y; a0.z += z00.z; a0.w += z00.w;
                a1.x += z01.x; a1.y += z01.y; a1.z += z01.z; a1.w += z01.w;
            }
            if (i1 < cnt) {
                a0.x += z10.x; a0.y += z10.y; a0.z += z10.z; a0.w += z10.w;
                a1.x += z11.x; a1.y += z11.y; a1.z += z11.z; a1.w += z11.w;
            }
            if (i2 < cnt) {
                a0.x += z20.x; a0.y += z20.y; a0.z += z20.z; a0.w += z20.w;
                a1.x += z21.x; a1.y += z21.y; a1.z += z21.z; a1.w += z21.w;
            }
            if (i3 < cnt) {
                a0.x += z30.x; a0.y += z30.y; a0.z += z30.z; a0.w += z30.w;
                a1.x += z31.x; a1.y += z31.y; a1.z += z31.z; a1.w += z31.w;
            }
        }
    }
#pragma unroll
    for (int off = 8; off < 64; off <<= 1) {
        a0.x += __shfl_xor(a0.x, off); a0.y += __shfl_xor(a0.y, off);
        a0.z += __shfl_xor(a0.z, off); a0.w += __shfl_xor(a0.w, off);
        a1.x += __shfl_xor(a1.x, off); a1.y += __shfl_xor(a1.y, off);
        a1.z += __shfl_xor(a1.z, off); a1.w += __shfl_xor(a1.w, off);
    }
    float sc = dis[node];
    const float4* b4 = (const float4*)bias;
    float4 b0 = b4[t], b1 = b4[t + 8];
    float4 v0, v1;
    v0.x = fmaxf(a0.x * sc + b0.x, 0.f); v0.y = fmaxf(a0.y * sc + b0.y, 0.f);
    v0.z = fmaxf(a0.z * sc + b0.z, 0.f); v0.w = fmaxf(a0.w * sc + b0.w, 0.f);
    v1.x = fmaxf(a1.x * sc + b1.x, 0.f); v1.y = fmaxf(a1.y * sc + b1.y, 0.f);
    v1.z = fmaxf(a1.z * sc + b1.z, 0.f); v1.w = fmaxf(a1.w * sc + b1.w, 0.f);
    if (g == 0) {
        float4* o4 = (float4*)out;
        o4[(size_t)node * 16 + t] = v0;
        o4[(size_t)node * 16 + t + 8] = v1;
    }
}

// ---------------- aggregate v7 + fused head ----------------
__global__ __launch_bounds__(256) void k_aggregate_head(const float* __restrict__ Hs,
                                                        const int* __restrict__ row_start,
                                                        const unsigned short* __restrict__ csr_src,
                                                        const float* __restrict__ dis,
                                                        const float* __restrict__ bias,
                                                        const float* __restrict__ Wl,
                                                        const float* __restrict__ bl, int N,
                                                        float* __restrict__ out) {
    const float4* Hs4 = (const float4*)Hs;
    int wave = threadIdx.x >> 6, lane = threadIdx.x & 63;
    int node = blockIdx.x * 4 + wave;
    if (node >= N) return;
    int t = lane & 7, g = lane >> 3;
    float4 a0 = make_float4(0.f, 0.f, 0.f, 0.f);
    float4 a1 = a0;
    if (g == 0) {
        a0 = Hs4[(size_t)node * 16 + t];
        a1 = Hs4[(size_t)node * 16 + t + 8];
    }
    int e0 = row_start[node], e1 = row_start[node + 1];
    for (int eb = e0; eb < e1; eb += 64) {
        int cnt = min(64, e1 - eb);
        int sv = (eb + lane < e1) ? (int)csr_src[eb + lane] : 0;
        for (int jb = 0; jb < cnt; jb += 32) {
            int i0 = jb + g, i1 = jb + 8 + g, i2 = jb + 16 + g, i3 = jb + 24 + g;
            int s0 = __shfl(sv, i0 < cnt ? i0 : 0);
            int s1 = __shfl(sv, i1 < cnt ? i1 : 0);
            int s2 = __shfl(sv, i2 < cnt ? i2 : 0);
            int s3 = __shfl(sv, i3 < cnt ? i3 : 0);
            size_t b0 = (size_t)s0 * 16, b1 = (size_t)s1 * 16;
            size_t b2 = (size_t)s2 * 16, b3 = (size_t)s3 * 16;
            float4 z00 = Hs4[b0 + t], z01 = Hs4[b0 + t + 8];
            float4 z10 = Hs4[b1 + t], z11 = Hs4[b1 + t + 8];
            float4 z20 = Hs4[b2 + t], z21 = Hs4[b2 + t + 8];
            float4 z30 = Hs4[b3 + t], z31 = Hs4[b3 + t + 8];
            if (i0 < cnt) {
                a0.x += z00.x; a0.y += z00.y; a0.z += z00.z; a0.w += z00.w;
                a1.x += z01.x; a1.y += z01.y; a1.z += z01.z; a1.w += z01.w;
            }
            if (i1 < cnt) {
                a0.x += z10.x; a0.y += z10.y; a0.z += z10.z; a0.w += z10.w;
                a1.x += z11.x; a1.y += z11.y; a1.z += z11.z; a1.w += z11.w;
            }
            if (i2 < cnt) {
                a0.x += z20.x; a0.y += z20.y; a0.z += z20.z; a0.w += z20.w;
                a1.x += z21.x; a1.y += z21.y; a1.z += z21.z; a1.w += z21.w;
            }
            if (i3 < cnt) {
                a0.x += z30.x; a0.y += z30.y; a0.z += z30.z; a0.w += z30.w;
                a1.x += z31.x; a1.y += z31.y; a1.z += z31.z; a1.w += z31.w;
            }
        }
    }
#pragma unroll
    for (int off = 8; off < 64; off <<= 1) {
        a0.x += __shfl_xor(a0.x, off); a0.y += __shfl_xor(a0.y, off);
        a0.z += __shfl_xor(a0.z, off); a0.w += __shfl_xor(a0.w, off);
        a1.x += __shfl_xor(a1.x, off); a1.y += __shfl_xor(a1.y, off);
        a1.z += __shfl_xor(a1.z, off); a1.w += __shfl_xor(a1.w, off);
    }
    float sc = dis[node];
    const float4* b4 = (const float4*)bias;
    float4 b0 = b4[t], b1 = b4[t + 8];
    float4 v0, v1;
    v0.x = fmaxf(a0.x * sc + b0.x, 0.f); v0.y = fmaxf(a0.y * sc + b0.y, 0.f);
    v0.z = fmaxf(a0.z * sc + b0.z, 0.f); v0.w = fmaxf(a0.w * sc + b0.w, 0.f);
    v1.x = fmaxf(a1.x * sc + b1.x, 0.f); v1.y = fmaxf(a1.y * sc + b1.y, 0.f);
    v1.z = fmaxf(a1.z * sc + b1.z, 0.f); v1.w = fmaxf(a1.w * sc + b1.w, 0.f);
    int c0 = 4 * t, c1 = 32 + 4 * t;
    float p0 = v0.x * Wl[(c0 + 0) * 2] + v0.y * Wl[(c0 + 1) * 2] +
               v0.z * Wl[(c0 + 2) * 2] + v0.w * Wl[(c0 + 3) * 2] +
               v1.x * Wl[(c1 + 0) * 2] + v1.y * Wl[(c1 + 1) * 2] +
               v1.z * Wl[(c1 + 2) * 2] + v1.w * Wl[(c1 + 3) * 2];
    float p1 = v0.x * Wl[(c0 + 0) * 2 + 1] + v0.y * Wl[(c0 + 1) * 2 + 1] +
               v0.z * Wl[(c0 + 2) * 2 + 1] + v0.w * Wl[(c0 + 3) * 2 + 1] +
               v1.x * Wl[(c1 + 0) * 2 + 1] + v1.y * Wl[(c1 + 1) * 2 + 1] +
               v1.z * Wl[(c1 + 2) * 2 + 1] + v1.w * Wl[(c1 + 3) * 2 + 1];
    p0 += __shfl_xor(p0, 1); p1 += __shfl_xor(p1, 1);
    p0 += __shfl_xor(p0, 2); p1 += __shfl_xor(p1, 2);
    p0 += __shfl_xor(p0, 4); p1 += __shfl_xor(p1, 4);
    if (lane == 0) {
        out[node * 2 + 0] = p0 + bl[0];
        out[node * 2 + 1] = p1 + bl[1];
    }
}

extern "C" void kernel_launch(void* const* d_in, const int* in_sizes, int n_in,
                              void* d_out, int out_size, void* d_ws, size_t ws_size,
                              hipStream_t stream) {
    const float* x  = (const float*)d_in[0];
    const int*   ei = (const int*)d_in[1];
    const float* W1 = (const float*)d_in[2];
    const float* b1 = (const float*)d_in[3];
    const float* W2 = (const float*)d_in[4];
    const float* b2 = (const float*)d_in[5];
    const float* Wl = (const float*)d_in[6];
    const float* bl = (const float*)d_in[7];

    const int N = in_sizes[0] / IN_DIM;   // 50000 (< 65536 required by packing)
    const int E = in_sizes[1] / 2;        // 800000
    const int* src = ei;
    const int* dst = ei + E;

    char* ws = (char*)d_ws;
    size_t off = 0;
    auto alloc = [&](size_t bytes) -> void* {
        void* p = ws + off;
        off = (off + bytes + 255) & ~(size_t)255;
        return p;
    };
    int*   bcnt      = (int*)alloc(256 * 4);
    int*   bbase     = (int*)alloc(257 * 4);
    int*   gcur      = (int*)alloc(256 * 4);
    int*   row_start = (int*)alloc(((size_t)N + 1) * 4);
    float* dis       = (float*)alloc((size_t)N * 4);
    unsigned short* csr_src = (unsigned short*)alloc((size_t)E * 2);
    float* bufA      = (float*)alloc((size_t)N * HID * 4);
    float* bufB      = (float*)alloc((size_t)N * HID * 4);
    unsigned* ebuf   = (unsigned*)bufA;  // alias: consumed by bin_sort before gemm1 writes bufA

    hipMemsetAsync(bcnt, 0, 256 * 4, stream);

    int eblk = (E + 4095) / 4096;  // 196
    int nb = (N + 255) / 256;      // 196
    k_bin_count<<<eblk, 256, 0, stream>>>(dst, E, bcnt);
    k_bucket_scan<<<1, 256, 0, stream>>>(bcnt, bbase, gcur, row_start, N, E);
    k_bin_scatter<<<eblk, 512, 0, stream>>>(src, dst, E, bbase, gcur, ebuf);
    k_bin_sort<<<nb, 512, 0, stream>>>(ebuf, bbase, N, E, row_start, dis, csr_src);

    const int gblk = (N + 63) / 64;  // 782
    const int nblk = (N + 3) / 4;
    k_gemm_scale<IN_DIM><<<gblk, 256, 0, stream>>>(x, W1, dis, N, bufA);
    k_aggregate<<<nblk, 256, 0, stream>>>(bufA, row_start, csr_src, dis, b1, N, bufB);
    k_gemm_scale<HID><<<gblk, 256, 0, stream>>>(bufB, W2, dis, N, bufA);
    k_aggregate_head<<<nblk, 256, 0, stream>>>(bufA, row_start, csr_src, dis, b2, Wl, bl, N,
                                               (float*)d_out);
}